// Round 11
// baseline (412.300 us; speedup 1.0000x reference)
//
#include <hip/hip_runtime.h>

// NSA attention.
// K0: init ck/cv. K1: K-split compress (fp32, atomics).
// K2: cmp attention + topk via f16 hi/lo MFMA (R9 verbatim).
// K3: monolithic MFMA flash, head-packed (TQ=8, rows 0-7 = head w,
//     rows 8-15 = head w+4), P aliased over Vrow (53 KB LDS, 3 blocks/CU),
//     register prefetch, direct epilogue write. No atomics, no partials.

#define S_LEN 1536
#define HQ    16
#define HKV   2
#define DH    128
#define TC    95
#define WIN   512
#define TQ    8
#define SCALE 0.08838834764831845f   // 1/sqrt(128)

typedef _Float16 f16;
typedef f16   f16x4 __attribute__((ext_vector_type(4)));
typedef f16   f16x8 __attribute__((ext_vector_type(8)));
typedef float f32x4 __attribute__((ext_vector_type(4)));

__device__ inline f16x8 cvt8(float4 A, float4 B) {
    f16x8 h;
    h[0]=(f16)A.x; h[1]=(f16)A.y; h[2]=(f16)A.z; h[3]=(f16)A.w;
    h[4]=(f16)B.x; h[5]=(f16)B.y; h[6]=(f16)B.z; h[7]=(f16)B.w;
    return h;
}
__device__ inline f16x8 cvt8s(float4 A, float4 B, float s) {
    f16x8 h;
    h[0]=(f16)(A.x*s); h[1]=(f16)(A.y*s); h[2]=(f16)(A.z*s); h[3]=(f16)(A.w*s);
    h[4]=(f16)(B.x*s); h[5]=(f16)(B.y*s); h[6]=(f16)(B.z*s); h[7]=(f16)(B.w*s);
    return h;
}

// ---------------------------------------------------------------- kernel 0
__global__ __launch_bounds__(256) void compress_init_kernel(
    const float* __restrict__ bk, const float* __restrict__ bv,
    float* __restrict__ ck, float* __restrict__ cv)
{
    int i = blockIdx.x * 256 + threadIdx.x;
    int which = i >= TC*HKV*DH;
    int j = i - which*(TC*HKV*DH);
    int d = j & 127;
    (which ? cv : ck)[j] = (which ? bv : bk)[d];
}

// ---------------------------------------------------------------- kernel 1
__global__ __launch_bounds__(256) void compress_partial_kernel(
    const float* __restrict__ kin, const float* __restrict__ vin,
    const float* __restrict__ Wk,  const float* __restrict__ Wv,
    const float* __restrict__ pek, const float* __restrict__ pev,
    float* __restrict__ ck, float* __restrict__ cv)
{
    const int t0    = blockIdx.x * 5;
    const int kv    = blockIdx.y >> 1;
    const int which = blockIdx.y & 1;
    const int kc    = blockIdx.z;
    const float* __restrict__ x  = which ? vin : kin;
    const float* __restrict__ W  = which ? Wv  : Wk;
    const float* __restrict__ pe = which ? pev : pek;
    float* __restrict__ outp     = which ? cv  : ck;
    const int tid = threadIdx.x;
    const int hh  = tid >> 7;
    const int d   = tid & 127;

    __shared__ float xs[2][5][128];
    __shared__ float racc[5][128];
    float acc[5] = {0.f, 0.f, 0.f, 0.f, 0.f};

    #pragma unroll
    for (int il = 0; il < 2; ++il) {
        const int l = kc*4 + hh*2 + il;
        float p = pe[l*DH + d];
        #pragma unroll
        for (int tt = 0; tt < 5; ++tt) {
            int row = (t0 + tt)*16 + l;
            xs[hh][tt][d] = x[(row*HKV + kv)*DH + d] + p;
        }
        __syncthreads();
        const float* wcol = W + l*DH*DH + d;
        #pragma unroll 8
        for (int dd = 0; dd < 128; ++dd) {
            float wv = wcol[dd*DH];
            #pragma unroll
            for (int tt = 0; tt < 5; ++tt) acc[tt] += xs[hh][tt][dd] * wv;
        }
        __syncthreads();
    }
    if (hh == 1) {
        #pragma unroll
        for (int tt = 0; tt < 5; ++tt) racc[tt][d] = acc[tt];
    }
    __syncthreads();
    if (hh == 0) {
        #pragma unroll
        for (int tt = 0; tt < 5; ++tt)
            atomicAdd(&outp[((t0 + tt)*HKV + kv)*DH + d], acc[tt] + racc[tt][d]);
    }
}

// ---------------------------------------------------------------- kernel 2
__global__ __launch_bounds__(256) void cmp_attn_mfma(
    const float* __restrict__ q, const float* __restrict__ ck,
    const float* __restrict__ cv, float* __restrict__ cmp_o,
    unsigned int* __restrict__ blk_mask)
{
    const int s0   = blockIdx.x * 8;
    const int kv   = blockIdx.y;
    const int tid  = threadIdx.x;
    const int w    = tid >> 6;
    const int lane = tid & 63;
    const int quad = lane >> 4;
    const int l4   = lane & 15;

    __shared__ __align__(16) char BUF[52736];
    f16* __restrict__ CKH = (f16*)BUF;             // [96][136] hi
    f16* __restrict__ CKL = (f16*)(BUF + 26112);   // [96][136] lo
    f16* __restrict__ CVR = (f16*)BUF;             // [96][136]
    f16* __restrict__ CVT = (f16*)(BUF + 26112);   // [128][104]
    f16*   __restrict__ Pw = (f16*)BUF + w*1664;   // per-wave P [16][104]
    float* __restrict__ SC = (float*)(BUF + 13312);// [8][96]
    float* __restrict__ PO = (float*)(BUF + 16384);// [8][24]

    #pragma unroll
    for (int i = 0; i < 6; ++i) {
        int idx = i*256 + tid;
        int row = idx >> 4, cg = idx & 15;
        float4 A = make_float4(0.f,0.f,0.f,0.f), B = A;
        if (row < TC) {
            const float* src = ck + ((size_t)(row*HKV + kv))*DH + cg*8;
            A = *(const float4*)src; B = *(const float4*)(src + 4);
        }
        f16x8 h = cvt8(A, B);
        f16x8 l;
        l[0]=(f16)(A.x-(float)h[0]); l[1]=(f16)(A.y-(float)h[1]);
        l[2]=(f16)(A.z-(float)h[2]); l[3]=(f16)(A.w-(float)h[3]);
        l[4]=(f16)(B.x-(float)h[4]); l[5]=(f16)(B.y-(float)h[5]);
        l[6]=(f16)(B.z-(float)h[6]); l[7]=(f16)(B.w-(float)h[7]);
        *(f16x8*)&CKH[row*136 + cg*8] = h;
        *(f16x8*)&CKL[row*136 + cg*8] = l;
    }

    const int qrow_local = w*16 + l4;
    const int sA = s0 + (qrow_local >> 3);
    const int hA = qrow_local & 7;
    f16x8 aqh[4], aql[4];
    {
        const float* qrow = q + ((size_t)(sA*HQ + kv*8 + hA))*DH;
        #pragma unroll
        for (int ks = 0; ks < 4; ++ks) {
            float4 A = *(const float4*)(qrow + ks*32 + quad*8);
            float4 B = *(const float4*)(qrow + ks*32 + quad*8 + 4);
            A.x*=SCALE; A.y*=SCALE; A.z*=SCALE; A.w*=SCALE;
            B.x*=SCALE; B.y*=SCALE; B.z*=SCALE; B.w*=SCALE;
            f16x8 h = cvt8(A, B);
            f16x8 l;
            l[0]=(f16)(A.x-(float)h[0]); l[1]=(f16)(A.y-(float)h[1]);
            l[2]=(f16)(A.z-(float)h[2]); l[3]=(f16)(A.w-(float)h[3]);
            l[4]=(f16)(B.x-(float)h[4]); l[5]=(f16)(B.y-(float)h[5]);
            l[6]=(f16)(B.z-(float)h[6]); l[7]=(f16)(B.w-(float)h[7]);
            aqh[ks] = h; aql[ks] = l;
        }
    }
    __syncthreads();

    f32x4 sc[6];
    #pragma unroll
    for (int nt = 0; nt < 6; ++nt) {
        sc[nt] = (f32x4){0.f,0.f,0.f,0.f};
        #pragma unroll
        for (int ks = 0; ks < 4; ++ks) {
            f16x8 bh = *(const f16x8*)&CKH[(nt*16 + l4)*136 + ks*32 + quad*8];
            f16x8 bl = *(const f16x8*)&CKL[(nt*16 + l4)*136 + ks*32 + quad*8];
            sc[nt] = __builtin_amdgcn_mfma_f32_16x16x32_f16(aqh[ks], bh, sc[nt], 0, 0, 0);
            sc[nt] = __builtin_amdgcn_mfma_f32_16x16x32_f16(aql[ks], bh, sc[nt], 0, 0, 0);
            sc[nt] = __builtin_amdgcn_mfma_f32_16x16x32_f16(aqh[ks], bl, sc[nt], 0, 0, 0);
        }
    }
    __syncthreads();

    #pragma unroll
    for (int i = 0; i < 6; ++i) {
        int idx = i*256 + tid;
        int row = idx >> 4, cg = idx & 15;
        float4 A = make_float4(0.f,0.f,0.f,0.f), B = A;
        if (row < TC) {
            const float* src = cv + ((size_t)(row*HKV + kv))*DH + cg*8;
            A = *(const float4*)src; B = *(const float4*)(src + 4);
        }
        *(f16x8*)&CVR[row*136 + cg*8] = cvt8(A, B);
    }
    __syncthreads();
    #pragma unroll
    for (int i = 0; i < 6; ++i) {
        int idx = i*256 + tid;
        int d = idx & 127, tc = idx >> 7;
        f16x8 h;
        #pragma unroll
        for (int j = 0; j < 8; ++j) h[j] = CVR[(tc*8 + j)*136 + d];
        *(f16x8*)&CVT[d*104 + tc*8] = h;
    }
    __syncthreads();

    const int s_q = s0 + 2*w + (quad >> 1);
    const int nv  = (s_q >= 31) ? (((s_q - 31) >> 4) + 1) : 0;
    bool valid[6];
    #pragma unroll
    for (int nt = 0; nt < 6; ++nt) valid[nt] = (nt*16 + l4) < nv;

    float pn[6][4];
    #pragma unroll
    for (int r = 0; r < 4; ++r) {
        float m = -3.4e38f;
        #pragma unroll
        for (int nt = 0; nt < 6; ++nt) m = fmaxf(m, valid[nt] ? sc[nt][r] : -3.4e38f);
        #pragma unroll
        for (int off = 1; off < 16; off <<= 1) m = fmaxf(m, __shfl_xor(m, off));
        float s = 0.f;
        #pragma unroll
        for (int nt = 0; nt < 6; ++nt) {
            float e = valid[nt] ? __expf(sc[nt][r] - m) : 0.f;
            pn[nt][r] = e;
            s += e;
        }
        #pragma unroll
        for (int off = 1; off < 16; off <<= 1) s += __shfl_xor(s, off);
        const float inv = 1.f / fmaxf(s, 1e-9f);
        #pragma unroll
        for (int nt = 0; nt < 6; ++nt) pn[nt][r] *= inv;
    }

    #pragma unroll
    for (int nt = 0; nt < 6; ++nt) {
        #pragma unroll
        for (int r = 0; r < 4; ++r)
            Pw[(quad*4 + r)*104 + nt*16 + l4] = (f16)pn[nt][r];
        float scq = pn[nt][0] + pn[nt][1] + pn[nt][2] + pn[nt][3];
        scq += __shfl_xor(scq, 16);
        if ((quad & 1) == 0)
            SC[(w*2 + (quad >> 1))*96 + nt*16 + l4] = scq;
    }

    {
        int qi = lane >> 5;
        int o  = lane & 31;
        bool sel = false;
        if (o < 24) {
            float acc = 0.f, cnt = 0.f;
            #pragma unroll
            for (int j = 0; j < 5; ++j) {
                int wd = o*4 + j;
                if (wd < TC) { acc += SC[(w*2 + qi)*96 + wd]; cnt += 1.f; }
            }
            PO[(w*2 + qi)*24 + o] = acc / cnt;
        }
        if (o < 24) {
            float pvv = PO[(w*2 + qi)*24 + o];
            int rank = 0;
            #pragma unroll
            for (int j = 0; j < 24; ++j) {
                float pj = PO[(w*2 + qi)*24 + j];
                rank += ((pj > pvv) || (pj == pvv && j < o)) ? 1 : 0;
            }
            sel = rank < 16;
        }
        unsigned long long b = __ballot(sel);
        if (lane == 0) {
            blk_mask[kv*S_LEN + s0 + 2*w]     = (unsigned int)(b & 0xFFFFFFull);
            blk_mask[kv*S_LEN + s0 + 2*w + 1] = (unsigned int)((b >> 32) & 0xFFFFFFull);
        }
    }

    f32x4 O[8];
    #pragma unroll
    for (int nf = 0; nf < 8; ++nf) O[nf] = (f32x4){0.f,0.f,0.f,0.f};
    #pragma unroll
    for (int ks2 = 0; ks2 < 3; ++ks2) {
        f16x8 ap = *(const f16x8*)&Pw[l4*104 + ks2*32 + quad*8];
        #pragma unroll
        for (int nf = 0; nf < 8; ++nf) {
            f16x8 bv = *(const f16x8*)&CVT[(nf*16 + l4)*104 + ks2*32 + quad*8];
            O[nf] = __builtin_amdgcn_mfma_f32_16x16x32_f16(ap, bv, O[nf], 0, 0, 0);
        }
    }
    #pragma unroll
    for (int r = 0; r < 4; ++r) {
        const int h_r = (quad & 1)*4 + r;
        const size_t base = ((size_t)(s_q*HQ + kv*8 + h_r))*DH;
        #pragma unroll
        for (int nf = 0; nf < 8; ++nf)
            cmp_o[base + nf*16 + l4] = O[nf][r];
    }
}

// ---------------------------------------------------------------- kernel 3
// Head-packed monolith: grid (192, kv). 256 thr = 4 waves; wave w packs
// head w (rows 0-7, queries t0..t0+7) and head w+4 (rows 8-15). Both
// branches; P aliased over Vrow (53 KB LDS); direct epilogue write.
__global__ __launch_bounds__(256, 3) void main_attn_mfma(
    const float* __restrict__ q, const float* __restrict__ kg,
    const float* __restrict__ vg, const float* cmp_o,   // aliases out!
    const unsigned int* __restrict__ blk_mask,
    const float* __restrict__ Wg, const float* __restrict__ bg,
    float* out)
{
    const int t0   = (S_LEN/TQ - 1 - blockIdx.x) * TQ;   // big tiles first
    const int kv   = blockIdx.y;
    const int tid  = threadIdx.x;
    const int w    = tid >> 6;
    const int lane = tid & 63;
    const int quad = lane >> 4;
    const int l4   = lane & 15;

    __shared__ __align__(16) f16 Klds[64*136];   // 17408 B
    __shared__ __align__(16) f16 VP[64*136];     // 17408 B: Vrow, then P
    __shared__ __align__(16) f16 Vt[128*72];     // 18432 B  (53248 total)
    f16* __restrict__ Pw = VP + w*1152;          // per-wave P [16][72]

    // Q A-frags: row l4 -> query t0+(l4&7), head w + 4*(l4>>3)
    f16x8 aq[4];
    {
        const float* qrow = q + ((size_t)((t0 + (l4 & 7))*HQ + kv*8 + w + (l4 >> 3)*4))*DH;
        #pragma unroll
        for (int ks = 0; ks < 4; ++ks) {
            float4 A = *(const float4*)(qrow + ks*32 + quad*8);
            float4 B = *(const float4*)(qrow + ks*32 + quad*8 + 4);
            aq[ks] = cvt8s(A, B, SCALE);
        }
    }

    int srow[4]; int headc[4]; unsigned selm[4];
    #pragma unroll
    for (int r = 0; r < 4; ++r) {
        int row = quad*4 + r;
        srow[r]  = t0 + (row & 7);
        headc[r] = kv*8 + w + (row >> 3)*4;
        selm[r]  = blk_mask[kv*S_LEN + srow[r]];
    }
    unsigned um = 0;
    for (int i = 0; i < TQ; ++i) um |= blk_mask[kv*S_LEN + t0 + i];

    f32x4 o_s[8], o_w[8];
    #pragma unroll
    for (int nf = 0; nf < 8; ++nf) {
        o_s[nf] = (f32x4){0.f,0.f,0.f,0.f};
        o_w[nf] = (f32x4){0.f,0.f,0.f,0.f};
    }
    float m_s[4], l_s[4], m_w[4], l_w[4];
    #pragma unroll
    for (int r = 0; r < 4; ++r) { m_s[r]=-1e30f; l_s[r]=0.f; m_w[r]=-1e30f; l_w[r]=0.f; }

    const int nkb = ((t0 + TQ - 1) >> 6) + 1;
    const int wlo_tile = t0 - WIN + 1;

    unsigned act = 0;
    for (int kb2 = 0; kb2 < nkb; ++kb2) {
        bool a = ((um >> kb2) & 1u) || ((kb2*64 + 63) >= wlo_tile);
        if (a) act |= (1u << kb2);
    }
    // act always nonzero: block 0 is selected by tie-break for early rows,
    // and the window always covers kb = nkb-1.

    int key_[4], cg_[4];
    #pragma unroll
    for (int i = 0; i < 4; ++i) { int idx = i*256 + tid; key_[i] = idx >> 4; cg_[i] = idx & 15; }

    float4 pkA[4], pkB[4], pvA[4], pvB[4];
    int kb = __builtin_ctz(act); act &= act - 1;
    #pragma unroll
    for (int i = 0; i < 4; ++i) {
        const float* sK = kg + ((size_t)(kb*64 + key_[i])*HKV + kv)*DH + cg_[i]*8;
        const float* sV = vg + ((size_t)(kb*64 + key_[i])*HKV + kv)*DH + cg_[i]*8;
        pkA[i] = *(const float4*)sK; pkB[i] = *(const float4*)(sK + 4);
        pvA[i] = *(const float4*)sV; pvB[i] = *(const float4*)(sV + 4);
    }

    while (true) {
        __syncthreads();   // prior compute done with Klds/Vt/P
        #pragma unroll
        for (int i = 0; i < 4; ++i) {
            *(f16x8*)&Klds[key_[i]*136 + cg_[i]*8] = cvt8(pkA[i], pkB[i]);
            *(f16x8*)&VP[key_[i]*136 + cg_[i]*8]   = cvt8(pvA[i], pvB[i]);
        }
        __syncthreads();

        const int cur = kb;
        const bool more = (act != 0);
        if (more) {
            kb = __builtin_ctz(act); act &= act - 1;
            #pragma unroll
            for (int i = 0; i < 4; ++i) {
                const float* sK = kg + ((size_t)(kb*64 + key_[i])*HKV + kv)*DH + cg_[i]*8;
                const float* sV = vg + ((size_t)(kb*64 + key_[i])*HKV + kv)*DH + cg_[i]*8;
                pkA[i] = *(const float4*)sK; pkB[i] = *(const float4*)(sK + 4);
                pvA[i] = *(const float4*)sV; pvB[i] = *(const float4*)(sV + 4);
            }
        }

        // transpose VP(Vrow)[key][d] -> Vt[d][key]
        #pragma unroll
        for (int i = 0; i < 4; ++i) {
            int idx = i*256 + tid;
            int d = idx & 127, kg8 = idx >> 7;
            f16x8 h;
            #pragma unroll
            for (int j = 0; j < 8; ++j) h[j] = VP[(kg8*8 + j)*136 + d];
            *(f16x8*)&Vt[d*72 + kg8*8] = h;
        }
        __syncthreads();   // Vrow dead; VP now usable as P

        // S = Q K^T (pre-scaled)
        f32x4 sc[4];
        #pragma unroll
        for (int nt = 0; nt < 4; ++nt) {
            sc[nt] = (f32x4){0.f,0.f,0.f,0.f};
            #pragma unroll
            for (int ks = 0; ks < 4; ++ks) {
                f16x8 bk = *(const f16x8*)&Klds[(nt*16 + l4)*136 + ks*32 + quad*8];
                sc[nt] = __builtin_amdgcn_mfma_f32_16x16x32_f16(aq[ks], bk, sc[nt], 0, 0, 0);
            }
        }

        const int keyb = cur*64;
        const bool any_sel = (um >> cur) & 1u;
        const bool any_win = (keyb + 63) >= wlo_tile;
        // ================= branch SEL =================
        if (any_sel) {
            float rmax[4] = {-1e30f,-1e30f,-1e30f,-1e30f};
            #pragma unroll
            for (int nt = 0; nt < 4; ++nt) {
                int key = keyb + nt*16 + l4;
                #pragma unroll
                for (int r = 0; r < 4; ++r) {
                    bool ok = (key <= srow[r]) && ((selm[r] >> cur) & 1u);
                    rmax[r] = fmaxf(rmax[r], ok ? sc[nt][r] : -1e30f);
                }
            }
            float alpha[4];
            #pragma unroll
            for (int r = 0; r < 4; ++r) {
                #pragma unroll
                for (int off = 1; off < 16; off <<= 1)
                    rmax[r] = fmaxf(rmax[r], __shfl_xor(rmax[r], off));
                float nm = fmaxf(m_s[r], rmax[r]);
                alpha[r] = __expf(m_s[r] - nm);
                m_s[r] = nm;
            }
            float rs[4] = {0.f,0.f,0.f,0.f};
            #pragma unroll
            for (int nt = 0; nt < 4; ++nt) {
                int key = keyb + nt*16 + l4;
                #pragma unroll
                for (int r = 0; r < 4; ++r) {
                    bool ok = (key <= srow[r]) && ((selm[r] >> cur) & 1u);
                    float p = ok ? __expf(sc[nt][r] - m_s[r]) : 0.f;
                    rs[r] += p;
                    Pw[(quad*4 + r)*72 + nt*16 + l4] = (f16)p;
                }
            }
            #pragma unroll
            for (int r = 0; r < 4; ++r) {
                #pragma unroll
                for (int off = 1; off < 16; off <<= 1) rs[r] += __shfl_xor(rs[r], off);
                l_s[r] = l_s[r]*alpha[r] + rs[r];
            }
            #pragma unroll
            for (int nf = 0; nf < 8; ++nf) {
                #pragma unroll
                for (int r = 0; r < 4; ++r) o_s[nf][r] *= alpha[r];
            }
            #pragma unroll
            for (int ks2 = 0; ks2 < 2; ++ks2) {
                f16x8 ap = *(const f16x8*)&Pw[l4*72 + ks2*32 + quad*8];
                #pragma unroll
                for (int nf = 0; nf < 8; ++nf) {
                    f16x8 bv = *(const f16x8*)&Vt[(nf*16 + l4)*72 + ks2*32 + quad*8];
                    o_s[nf] = __builtin_amdgcn_mfma_f32_16x16x32_f16(ap, bv, o_s[nf], 0, 0, 0);
                }
            }
        }
        // ================= branch WIN =================
        if (any_win) {
            float rmax[4] = {-1e30f,-1e30f,-1e30f,-1e30f};
            #pragma unroll
            for (int nt = 0; nt < 4; ++nt) {
                int key = keyb + nt*16 + l4;
                #pragma unroll
                for (int r = 0; r < 4; ++r) {
                    bool ok = (key <= srow[r]) && (key > srow[r] - WIN);
                    rmax[r] = fmaxf(rmax[r], ok ? sc[nt][r] : -1e30f);
                }
            }
            float alpha[4];
            #pragma unroll
            for (int r = 0; r < 4; ++r) {
                #pragma unroll
                for (int off = 1; off < 16; off <<= 1)
                    rmax[r] = fmaxf(rmax[r], __shfl_xor(rmax[r], off));
                float nm = fmaxf(m_w[r], rmax[r]);
                alpha[r] = __expf(m_w[r] - nm);
                m_w[r] = nm;
            }
            float rs[4] = {0.f,0.f,0.f,0.f};
            #pragma unroll
            for (int nt = 0; nt < 4; ++nt) {
                int key = keyb + nt*16 + l4;
                #pragma unroll
                for (int r = 0; r < 4; ++r) {
                    bool ok = (key <= srow[r]) && (key > srow[r] - WIN);
                    float p = ok ? __expf(sc[nt][r] - m_w[r]) : 0.f;
                    rs[r] += p;
                    Pw[(quad*4 + r)*72 + nt*16 + l4] = (f16)p;
                }
            }
            #pragma unroll
            for (int r = 0; r < 4; ++r) {
                #pragma unroll
                for (int off = 1; off < 16; off <<= 1) rs[r] += __shfl_xor(rs[r], off);
                l_w[r] = l_w[r]*alpha[r] + rs[r];
            }
            #pragma unroll
            for (int nf = 0; nf < 8; ++nf) {
                #pragma unroll
                for (int r = 0; r < 4; ++r) o_w[nf][r] *= alpha[r];
            }
            #pragma unroll
            for (int ks2 = 0; ks2 < 2; ++ks2) {
                f16x8 ap = *(const f16x8*)&Pw[l4*72 + ks2*32 + quad*8];
                #pragma unroll
                for (int nf = 0; nf < 8; ++nf) {
                    f16x8 bv = *(const f16x8*)&Vt[(nf*16 + l4)*72 + ks2*32 + quad*8];
                    o_w[nf] = __builtin_amdgcn_mfma_f32_16x16x32_f16(ap, bv, o_w[nf], 0, 0, 0);
                }
            }
        }

        if (!more) break;
    }

    // epilogue: all three gates, read cmp_o, direct write (one writer/elem)
    #pragma unroll
    for (int r = 0; r < 4; ++r) {
        const float inv_s = 1.f / fmaxf(l_s[r], 1e-9f);
        const float inv_w = 1.f / fmaxf(l_w[r], 1e-9f);
        float p0 = 0.f, p1 = 0.f, p2 = 0.f;
        const float* qrow = q + ((size_t)(srow[r]*HQ + headc[r]))*DH + l4*8;
        #pragma unroll
        for (int j = 0; j < 8; ++j) {
            float qv = qrow[j];
            int d = l4*8 + j;
            p0 += qv * Wg[d*3 + 0];
            p1 += qv * Wg[d*3 + 1];
            p2 += qv * Wg[d*3 + 2];
        }
        #pragma unroll
        for (int off = 1; off < 16; off <<= 1) {
            p0 += __shfl_xor(p0, off);
            p1 += __shfl_xor(p1, off);
            p2 += __shfl_xor(p2, off);
        }
        const float g0 = 1.f/(1.f + __expf(-(p0 + bg[0])));
        const float g1 = 1.f/(1.f + __expf(-(p1 + bg[1])));
        const float g2 = 1.f/(1.f + __expf(-(p2 + bg[2])));
        #pragma unroll
        for (int nf = 0; nf < 8; ++nf) {
            size_t oi = ((size_t)(srow[r]*HQ + headc[r]))*DH + nf*16 + l4;
            float cm = cmp_o[oi];   // read before overwrite
            out[oi] = g0*o_s[nf][r]*inv_s + g1*o_w[nf][r]*inv_w + g2*cm;
        }
    }
}

// ---------------------------------------------------------------- launcher
extern "C" void kernel_launch(void* const* d_in, const int* in_sizes, int n_in,
                              void* d_out, int out_size, void* d_ws, size_t ws_size,
                              hipStream_t stream) {
    const float* q   = (const float*)d_in[0];
    const float* k   = (const float*)d_in[1];
    const float* v   = (const float*)d_in[2];
    const float* Wk  = (const float*)d_in[3];
    const float* bk  = (const float*)d_in[4];
    const float* Wv  = (const float*)d_in[5];
    const float* bv  = (const float*)d_in[6];
    const float* pek = (const float*)d_in[7];
    const float* pev = (const float*)d_in[8];
    const float* Wg  = (const float*)d_in[9];
    const float* bg  = (const float*)d_in[10];
    float* out = (float*)d_out;

    char* ws = (char*)d_ws;
    float* ck = (float*)ws;                                //  97,280 B
    float* cv = (float*)(ws + 98304);                      //  97,280 B
    unsigned int* blk_mask = (unsigned int*)(ws + 196608); //  12,288 B
    float* cmp_o = out;

    compress_init_kernel<<<dim3(190), 256, 0, stream>>>(bk, bv, ck, cv);
    compress_partial_kernel<<<dim3(19, 4, 8), 256, 0, stream>>>(
        k, v, Wk, Wv, pek, pev, ck, cv);
    cmp_attn_mfma<<<dim3(S_LEN/8, HKV), 256, 0, stream>>>(
        q, ck, cv, cmp_o, blk_mask);
    main_attn_mfma<<<dim3(S_LEN/TQ, HKV), 256, 0, stream>>>(
        q, k, v, cmp_o, blk_mask, Wg, bg, out);
}